// Round 7
// baseline (132.979 us; speedup 1.0000x reference)
//
#include <hip/hip_runtime.h>
#include <hip/hip_bf16.h>

#define NN 512
#define DD 128

typedef __bf16 bf16x8 __attribute__((ext_vector_type(8)));
typedef float f32x4 __attribute__((ext_vector_type(4)));

static __device__ __forceinline__ f32x4 mfma16(bf16x8 a, bf16x8 b, f32x4 c) {
  return __builtin_amdgcn_mfma_f32_16x16x32_bf16(a, b, c, 0, 0, 0);
}

// -------- phase 0 (fused): w1t transpose + hjp + cnt --------
// block j (of 512): hjp[j] = h[j]@w1_h + b1; 32 w1t elements; cnt[j].
__global__ void k_pre(const float* __restrict__ h,
                      const float* __restrict__ msg_w1,
                      const float* __restrict__ msg_b1,
                      const int* __restrict__ emask,
                      __bf16* __restrict__ w1t, float* __restrict__ hjp,
                      float* __restrict__ cnt) {
  __shared__ float hr[128];
  __shared__ int csum;
  int j = blockIdx.x, t = threadIdx.x;
  if (t == 0) csum = 0;
  hr[t] = h[j * 128 + t];
  __syncthreads();
  float acc = msg_b1[t];
  #pragma unroll 8
  for (int k = 0; k < 128; k++) acc += hr[k] * msg_w1[k * 128 + t];
  hjp[j * 128 + t] = acc;
  // w1t[e][k] = msg_w1[128+k][e] : 32 elements per block
  if (t < 32) {
    int tt = j * 32 + t;
    int e = tt >> 7, k = tt & 127;
    w1t[e * 128 + k] = (__bf16)msg_w1[(128 + k) * 128 + e];
  }
  // cnt[j] = sum_r emask[r][j]
  int s = 0;
  #pragma unroll
  for (int r = 0; r < 4; r++) s += emask[(t * 4 + r) * NN + j] ? 1 : 0;
  #pragma unroll
  for (int off = 32; off > 0; off >>= 1) s += __shfl_down(s, off, 64);
  if ((t & 63) == 0) atomicAdd(&csum, s);
  __syncthreads();
  if (t == 0) cnt[j] = (float)csum;
}

// ---------------- phase 1: T[i][e] = sum_j mask[j,i]*silu(pre[j,i,e]) ----
// GEMM2 hoisted out of the N^2 loop (linearity). 256-thread blocks,
// __launch_bounds__(256,4): 128-unified-VGPR cap; live set ~50 arch +
// ~40 acc (Tacc 32 + p0/p1 8) fits cleanly -> 4 waves/SIMD, 4 blocks/CU.
// LDS: w1t[128][136] bf16 (34816 B), reused as 4 x [8][132] f32 reduce bufs.
#define LDS_BYTES 34816

__global__ __launch_bounds__(256, 4) void k_main(
    const float* __restrict__ rel, const int* __restrict__ emask,
    const float* __restrict__ hjp, const __bf16* __restrict__ w1t_g,
    float* __restrict__ partial) {
  extern __shared__ char smem[];
  __bf16* w1t = (__bf16*)smem;
  const int tid = threadIdx.x;
  const int wave = tid >> 6;
  const int lane = tid & 63;
  const int l15 = lane & 15;
  const int q = lane >> 4;

  // stage w1t into padded LDS (row stride 272B): 256 thr x 8 bf16 x 8
  {
    int t = tid * 8;
    #pragma unroll
    for (int t0 = 0; t0 < 8; t0++) {
      int tt = t + t0 * 2048;
      int e = tt >> 7, k8 = tt & 127;
      *(bf16x8*)(w1t + e * 136 + k8) = *(const bf16x8*)(w1t_g + e * 128 + k8);
    }
  }
  __syncthreads();

  const int it = blockIdx.x >> 5;    // 0..31 : 16-row i-tile
  const int jc = blockIdx.x & 31;    // 0..31 : 16-col j-chunk
  const int irow = it * 16;

  // Tacc[ef][r] = T[i = l15][e = ef*16 + q*4 + r]  (f32, this wave's 4 j's)
  f32x4 Tacc[8];
  #pragma unroll
  for (int ef = 0; ef < 8; ef++) {
    f32x4 z = {0.f, 0.f, 0.f, 0.f};
    Tacc[ef] = z;
  }

  const int jbase = jc * 16 + wave * 4;
  #pragma unroll 1
  for (int jj = 0; jj < 4; jj++) {
    const int j = jbase + jj;

    // load 16 rel rows (GEMM1 B-operand): rel[j][irow+l15][kc*32+q*8 ..]
    bf16x8 bfr[4];
    const float* rowp = rel + ((size_t)j * NN + irow + l15) * DD + q * 8;
    #pragma unroll
    for (int kc = 0; kc < 4; kc++) {
      f32x4 x0 = *(const f32x4*)(rowp + kc * 32);
      f32x4 x1 = *(const f32x4*)(rowp + kc * 32 + 4);
      bf16x8 bb;
      bb[0] = (__bf16)x0[0]; bb[1] = (__bf16)x0[1];
      bb[2] = (__bf16)x0[2]; bb[3] = (__bf16)x0[3];
      bb[4] = (__bf16)x1[0]; bb[5] = (__bf16)x1[1];
      bb[6] = (__bf16)x1[2]; bb[7] = (__bf16)x1[3];
      bfr[kc] = bb;
    }

    float ms = emask[(size_t)j * NN + irow + l15] ? 1.f : 0.f;
    const float* hj = hjp + (size_t)j * DD;

    // per eg: GEMM1 rows [32eg,32eg+32) -> silu -> masked accumulate
    #pragma unroll
    for (int eg = 0; eg < 4; eg++) {
      f32x4 p0 = {0.f, 0.f, 0.f, 0.f};
      f32x4 p1 = {0.f, 0.f, 0.f, 0.f};
      #pragma unroll
      for (int kc = 0; kc < 4; kc++) {
        bf16x8 aw0 = *(const bf16x8*)(w1t + (eg * 32 + l15) * 136 + kc * 32 + q * 8);
        bf16x8 aw1 = *(const bf16x8*)(w1t + (eg * 32 + 16 + l15) * 136 + kc * 32 + q * 8);
        p0 = mfma16(aw0, bfr[kc], p0);
        p1 = mfma16(aw1, bfr[kc], p1);
      }
      // lane holds pre[e = 32eg + q*4 + r][i = l15] (p0), e+16 (p1)
      f32x4 hv0 = *(const f32x4*)(hj + eg * 32 + q * 4);
      f32x4 hv1 = *(const f32x4*)(hj + eg * 32 + 16 + q * 4);
      #pragma unroll
      for (int r = 0; r < 4; r++) {
        float x0 = p0[r] + hv0[r];
        float x1 = p1[r] + hv1[r];
        Tacc[2 * eg][r]     += ms * x0 / (1.f + __expf(-x0));
        Tacc[2 * eg + 1][r] += ms * x1 / (1.f + __expf(-x1));
      }
    }
  }

  // cross-wave reduction: reuse w1t region as 4 x [8][132] f32 bufs.
  // Tacc[ef][r] = T[i=l15][e=ef*16+q*4+r]; two 8-row rounds over i.
  float* fbase = (float*)smem;
  float* fb = fbase + wave * (8 * 132);
  #pragma unroll
  for (int t = 0; t < 2; t++) {
    __syncthreads();   // round 0: all w1t reads done; round 1: prev reads done
    if ((l15 >> 3) == t) {
      #pragma unroll
      for (int ef = 0; ef < 8; ef++)
        *(f32x4*)(fb + (l15 & 7) * 132 + ef * 16 + q * 4) = Tacc[ef];
    }
    __syncthreads();
    int row8 = tid >> 5;         // 0..7
    int e4 = (tid & 31) << 2;    // 0..124 step 4
    f32x4 s = {0.f, 0.f, 0.f, 0.f};
    #pragma unroll
    for (int w = 0; w < 4; w++)
      s += *(const f32x4*)(fbase + w * (8 * 132) + row8 * 132 + e4);
    *(f32x4*)(partial + ((size_t)jc * NN + irow + t * 8 + row8) * DD + e4) = s;
  }
}

// ------- phase 2: T-reduce + GEMM2(f32) + update MLP + LayerNorm -------
__global__ void k_update(const float* __restrict__ h, const float* __restrict__ partial,
                         const float* __restrict__ w2, const float* __restrict__ b2,
                         const float* __restrict__ cnt,
                         const float* __restrict__ uw1, const float* __restrict__ ub1,
                         const float* __restrict__ uw2, const float* __restrict__ ub2,
                         const float* __restrict__ g, const float* __restrict__ bb,
                         float* __restrict__ out) {
  __shared__ float Trow[128];
  __shared__ float uin[256];
  __shared__ float zl[128];
  __shared__ float ss[4];
  int i = blockIdx.x, t = threadIdx.x;
  float hv = h[i * 128 + t];
  float ts = 0.f;
  #pragma unroll
  for (int c = 0; c < 32; c++) ts += partial[((size_t)c * NN + i) * DD + t];
  Trow[t] = ts;
  __syncthreads();
  // agg[d] = T[i,:] @ w2[:,d] + cnt[i]*b2[d]   (f32 GEMM2, hoisted)
  float a = cnt[i] * b2[t];
  #pragma unroll 8
  for (int e = 0; e < 128; e++) a += Trow[e] * w2[e * 128 + t];
  uin[t] = hv;
  uin[128 + t] = a;
  __syncthreads();
  float z = ub1[t];
  #pragma unroll 8
  for (int k = 0; k < 256; k++) z += uin[k] * uw1[k * 128 + t];
  z = z / (1.f + __expf(-z));
  zl[t] = z;
  __syncthreads();
  float dl = ub2[t];
  #pragma unroll 8
  for (int k = 0; k < 128; k++) dl += zl[k] * uw2[k * 128 + t];
  float x = hv + dl;
  float s1 = x, s2 = x * x;
  #pragma unroll
  for (int off = 32; off > 0; off >>= 1) {
    s1 += __shfl_down(s1, off, 64);
    s2 += __shfl_down(s2, off, 64);
  }
  if ((t & 63) == 0) { ss[(t >> 6) * 2] = s1; ss[(t >> 6) * 2 + 1] = s2; }
  __syncthreads();
  s1 = ss[0] + ss[2];
  s2 = ss[1] + ss[3];
  float mu = s1 * (1.f / 128.f);
  float var = s2 * (1.f / 128.f) - mu * mu;
  out[i * 128 + t] = (x - mu) * rsqrtf(var + 1e-5f) * g[t] + bb[t];
}

extern "C" void kernel_launch(void* const* d_in, const int* in_sizes, int n_in,
                              void* d_out, int out_size, void* d_ws, size_t ws_size,
                              hipStream_t stream) {
  const float* h      = (const float*)d_in[0];
  const float* rel    = (const float*)d_in[1];
  const int*   emask  = (const int*)d_in[2];
  const float* msg_w1 = (const float*)d_in[3];
  const float* msg_b1 = (const float*)d_in[4];
  const float* msg_w2 = (const float*)d_in[5];
  const float* msg_b2 = (const float*)d_in[6];
  const float* upd_w1 = (const float*)d_in[7];
  const float* upd_b1 = (const float*)d_in[8];
  const float* upd_w2 = (const float*)d_in[9];
  const float* upd_b2 = (const float*)d_in[10];
  const float* ln_g   = (const float*)d_in[11];
  const float* ln_b   = (const float*)d_in[12];
  float* out = (float*)d_out;

  char* ws = (char*)d_ws;
  float*  hjp     = (float*)ws;                        // 262144 B
  __bf16* w1t     = (__bf16*)(ws + 262144);            // 32768 B
  float*  cnt     = (float*)(ws + 262144 + 32768);     // 2048 B
  float*  partial = (float*)(ws + 262144 + 36864);     // 32*512*128*4 = 8 MiB

  k_pre<<<512, 128, 0, stream>>>(h, msg_w1, msg_b1, emask, w1t, hjp, cnt);
  hipFuncSetAttribute((const void*)k_main,
                      hipFuncAttributeMaxDynamicSharedMemorySize, LDS_BYTES);
  k_main<<<1024, 256, LDS_BYTES, stream>>>(rel, emask, hjp, w1t, partial);
  k_update<<<512, 128, 0, stream>>>(h, partial, msg_w2, msg_b2, cnt,
                                    upd_w1, upd_b1, upd_w2, upd_b2,
                                    ln_g, ln_b, out);
}

// Round 8
// 65.185 us; speedup vs baseline: 2.0400x; 2.0400x over previous
//
#include <hip/hip_runtime.h>
#include <hip/hip_bf16.h>

#define NN 512
#define DD 128

typedef __bf16 bf16x8 __attribute__((ext_vector_type(8)));
typedef float f32x4 __attribute__((ext_vector_type(4)));

static __device__ __forceinline__ f32x4 mfma16(bf16x8 a, bf16x8 b, f32x4 c) {
  return __builtin_amdgcn_mfma_f32_16x16x32_bf16(a, b, c, 0, 0, 0);
}

// -------- phase 0 (fused): w1t transpose + hjp + cnt --------
__global__ void k_pre(const float* __restrict__ h,
                      const float* __restrict__ msg_w1,
                      const float* __restrict__ msg_b1,
                      const int* __restrict__ emask,
                      __bf16* __restrict__ w1t, float* __restrict__ hjp,
                      float* __restrict__ cnt) {
  __shared__ float hr[128];
  __shared__ int csum;
  int j = blockIdx.x, t = threadIdx.x;
  if (t == 0) csum = 0;
  hr[t] = h[j * 128 + t];
  __syncthreads();
  float acc = msg_b1[t];
  #pragma unroll 8
  for (int k = 0; k < 128; k++) acc += hr[k] * msg_w1[k * 128 + t];
  hjp[j * 128 + t] = acc;
  // w1t[e][k] = msg_w1[128+k][e] : 32 elements per block
  if (t < 32) {
    int tt = j * 32 + t;
    int e = tt >> 7, k = tt & 127;
    w1t[e * 128 + k] = (__bf16)msg_w1[(128 + k) * 128 + e];
  }
  // cnt[j] = sum_r emask[r][j]
  int s = 0;
  #pragma unroll
  for (int r = 0; r < 4; r++) s += emask[(t * 4 + r) * NN + j] ? 1 : 0;
  #pragma unroll
  for (int off = 32; off > 0; off >>= 1) s += __shfl_down(s, off, 64);
  if ((t & 63) == 0) atomicAdd(&csum, s);
  __syncthreads();
  if (t == 0) cnt[j] = (float)csum;
}

// ---------------- phase 1: T[i][e] = sum_j mask[j,i]*silu(pre[j,i,e]) ----
// GEMM2 hoisted out of the N^2 loop (linearity). 256-thread blocks.
// __launch_bounds__(256,2): unified cap 256. Empirical allocator law from
// R1-R7: cap 128 ((512,2)/(256,4)) -> 64/64 arch/acc split -> our ~90-reg
// VALU live set spills (88-270MB scratch traffic). Cap >=256 ((512,1) in
// R6) -> 128-arch split -> no spill. 34.8KB LDS + <=128 VGPR -> 2+ blocks/CU.
#define LDS_BYTES 34816

__global__ __launch_bounds__(256, 2) void k_main(
    const float* __restrict__ rel, const int* __restrict__ emask,
    const float* __restrict__ hjp, const __bf16* __restrict__ w1t_g,
    float* __restrict__ partial) {
  extern __shared__ char smem[];
  __bf16* w1t = (__bf16*)smem;
  const int tid = threadIdx.x;
  const int wave = tid >> 6;
  const int lane = tid & 63;
  const int l15 = lane & 15;
  const int q = lane >> 4;

  // stage w1t into padded LDS (row stride 272B): 256 thr x 8 bf16 x 8
  {
    int t = tid * 8;
    #pragma unroll
    for (int t0 = 0; t0 < 8; t0++) {
      int tt = t + t0 * 2048;
      int e = tt >> 7, k8 = tt & 127;
      *(bf16x8*)(w1t + e * 136 + k8) = *(const bf16x8*)(w1t_g + e * 128 + k8);
    }
  }
  __syncthreads();

  const int it = blockIdx.x >> 5;    // 0..31 : 16-row i-tile
  const int jc = blockIdx.x & 31;    // 0..31 : 16-col j-chunk
  const int irow = it * 16;

  // Tacc[ef][r] = T[i = l15][e = ef*16 + q*4 + r]  (f32, this wave's 4 j's)
  f32x4 Tacc[8];
  #pragma unroll
  for (int ef = 0; ef < 8; ef++) {
    f32x4 z = {0.f, 0.f, 0.f, 0.f};
    Tacc[ef] = z;
  }

  const int jbase = jc * 16 + wave * 4;
  #pragma unroll 1
  for (int jj = 0; jj < 4; jj++) {
    const int j = jbase + jj;

    // load 16 rel rows (GEMM1 B-operand): rel[j][irow+l15][kc*32+q*8 ..]
    bf16x8 bfr[4];
    const float* rowp = rel + ((size_t)j * NN + irow + l15) * DD + q * 8;
    #pragma unroll
    for (int kc = 0; kc < 4; kc++) {
      f32x4 x0 = *(const f32x4*)(rowp + kc * 32);
      f32x4 x1 = *(const f32x4*)(rowp + kc * 32 + 4);
      bf16x8 bb;
      bb[0] = (__bf16)x0[0]; bb[1] = (__bf16)x0[1];
      bb[2] = (__bf16)x0[2]; bb[3] = (__bf16)x0[3];
      bb[4] = (__bf16)x1[0]; bb[5] = (__bf16)x1[1];
      bb[6] = (__bf16)x1[2]; bb[7] = (__bf16)x1[3];
      bfr[kc] = bb;
    }

    float ms = emask[(size_t)j * NN + irow + l15] ? 1.f : 0.f;
    const float* hj = hjp + (size_t)j * DD;

    // per eg: GEMM1 rows [32eg,32eg+32) -> silu -> masked accumulate
    #pragma unroll
    for (int eg = 0; eg < 4; eg++) {
      f32x4 p0 = {0.f, 0.f, 0.f, 0.f};
      f32x4 p1 = {0.f, 0.f, 0.f, 0.f};
      #pragma unroll
      for (int kc = 0; kc < 4; kc++) {
        bf16x8 aw0 = *(const bf16x8*)(w1t + (eg * 32 + l15) * 136 + kc * 32 + q * 8);
        bf16x8 aw1 = *(const bf16x8*)(w1t + (eg * 32 + 16 + l15) * 136 + kc * 32 + q * 8);
        p0 = mfma16(aw0, bfr[kc], p0);
        p1 = mfma16(aw1, bfr[kc], p1);
      }
      // lane holds pre[e = 32eg + q*4 + r][i = l15] (p0), e+16 (p1)
      f32x4 hv0 = *(const f32x4*)(hj + eg * 32 + q * 4);
      f32x4 hv1 = *(const f32x4*)(hj + eg * 32 + 16 + q * 4);
      #pragma unroll
      for (int r = 0; r < 4; r++) {
        float x0 = p0[r] + hv0[r];
        float x1 = p1[r] + hv1[r];
        // silu via fast rcp: x * rcp(1+exp(-x)); v_rcp error ~1ulp << bf16 tol
        Tacc[2 * eg][r]     += ms * x0 * __builtin_amdgcn_rcpf(1.f + __expf(-x0));
        Tacc[2 * eg + 1][r] += ms * x1 * __builtin_amdgcn_rcpf(1.f + __expf(-x1));
      }
    }
  }

  // cross-wave reduction: reuse w1t region as 4 x [8][132] f32 bufs.
  // Tacc[ef][r] = T[i=l15][e=ef*16+q*4+r]; two 8-row rounds over i.
  float* fbase = (float*)smem;
  float* fb = fbase + wave * (8 * 132);
  #pragma unroll
  for (int t = 0; t < 2; t++) {
    __syncthreads();   // round 0: all w1t reads done; round 1: prev reads done
    if ((l15 >> 3) == t) {
      #pragma unroll
      for (int ef = 0; ef < 8; ef++)
        *(f32x4*)(fb + (l15 & 7) * 132 + ef * 16 + q * 4) = Tacc[ef];
    }
    __syncthreads();
    int row8 = tid >> 5;         // 0..7
    int e4 = (tid & 31) << 2;    // 0..124 step 4
    f32x4 s = {0.f, 0.f, 0.f, 0.f};
    #pragma unroll
    for (int w = 0; w < 4; w++)
      s += *(const f32x4*)(fbase + w * (8 * 132) + row8 * 132 + e4);
    *(f32x4*)(partial + ((size_t)jc * NN + irow + t * 8 + row8) * DD + e4) = s;
  }
}

// ------- phase 2: T-reduce + GEMM2(f32) + update MLP + LayerNorm -------
__global__ void k_update(const float* __restrict__ h, const float* __restrict__ partial,
                         const float* __restrict__ w2, const float* __restrict__ b2,
                         const float* __restrict__ cnt,
                         const float* __restrict__ uw1, const float* __restrict__ ub1,
                         const float* __restrict__ uw2, const float* __restrict__ ub2,
                         const float* __restrict__ g, const float* __restrict__ bb,
                         float* __restrict__ out) {
  __shared__ float Trow[128];
  __shared__ float uin[256];
  __shared__ float zl[128];
  __shared__ float ss[4];
  int i = blockIdx.x, t = threadIdx.x;
  float hv = h[i * 128 + t];
  float ts = 0.f;
  #pragma unroll
  for (int c = 0; c < 32; c++) ts += partial[((size_t)c * NN + i) * DD + t];
  Trow[t] = ts;
  __syncthreads();
  // agg[d] = T[i,:] @ w2[:,d] + cnt[i]*b2[d]   (f32 GEMM2, hoisted)
  float a = cnt[i] * b2[t];
  #pragma unroll 8
  for (int e = 0; e < 128; e++) a += Trow[e] * w2[e * 128 + t];
  uin[t] = hv;
  uin[128 + t] = a;
  __syncthreads();
  float z = ub1[t];
  #pragma unroll 8
  for (int k = 0; k < 256; k++) z += uin[k] * uw1[k * 128 + t];
  z = z / (1.f + __expf(-z));
  zl[t] = z;
  __syncthreads();
  float dl = ub2[t];
  #pragma unroll 8
  for (int k = 0; k < 128; k++) dl += zl[k] * uw2[k * 128 + t];
  float x = hv + dl;
  float s1 = x, s2 = x * x;
  #pragma unroll
  for (int off = 32; off > 0; off >>= 1) {
    s1 += __shfl_down(s1, off, 64);
    s2 += __shfl_down(s2, off, 64);
  }
  if ((t & 63) == 0) { ss[(t >> 6) * 2] = s1; ss[(t >> 6) * 2 + 1] = s2; }
  __syncthreads();
  s1 = ss[0] + ss[2];
  s2 = ss[1] + ss[3];
  float mu = s1 * (1.f / 128.f);
  float var = s2 * (1.f / 128.f) - mu * mu;
  out[i * 128 + t] = (x - mu) * rsqrtf(var + 1e-5f) * g[t] + bb[t];
}

extern "C" void kernel_launch(void* const* d_in, const int* in_sizes, int n_in,
                              void* d_out, int out_size, void* d_ws, size_t ws_size,
                              hipStream_t stream) {
  const float* h      = (const float*)d_in[0];
  const float* rel    = (const float*)d_in[1];
  const int*   emask  = (const int*)d_in[2];
  const float* msg_w1 = (const float*)d_in[3];
  const float* msg_b1 = (const float*)d_in[4];
  const float* msg_w2 = (const float*)d_in[5];
  const float* msg_b2 = (const float*)d_in[6];
  const float* upd_w1 = (const float*)d_in[7];
  const float* upd_b1 = (const float*)d_in[8];
  const float* upd_w2 = (const float*)d_in[9];
  const float* upd_b2 = (const float*)d_in[10];
  const float* ln_g   = (const float*)d_in[11];
  const float* ln_b   = (const float*)d_in[12];
  float* out = (float*)d_out;

  char* ws = (char*)d_ws;
  float*  hjp     = (float*)ws;                        // 262144 B
  __bf16* w1t     = (__bf16*)(ws + 262144);            // 32768 B
  float*  cnt     = (float*)(ws + 262144 + 32768);     // 2048 B
  float*  partial = (float*)(ws + 262144 + 36864);     // 32*512*128*4 = 8 MiB

  k_pre<<<512, 128, 0, stream>>>(h, msg_w1, msg_b1, emask, w1t, hjp, cnt);
  hipFuncSetAttribute((const void*)k_main,
                      hipFuncAttributeMaxDynamicSharedMemorySize, LDS_BYTES);
  k_main<<<1024, 256, LDS_BYTES, stream>>>(rel, emask, hjp, w1t, partial);
  k_update<<<512, 128, 0, stream>>>(h, partial, msg_w2, msg_b2, cnt,
                                    upd_w1, upd_b1, upd_w2, upd_b2,
                                    ln_g, ln_b, out);
}

// Round 9
// 60.941 us; speedup vs baseline: 2.1821x; 1.0696x over previous
//
#include <hip/hip_runtime.h>
#include <hip/hip_bf16.h>

#define NN 512
#define DD 128

typedef __bf16 bf16x8 __attribute__((ext_vector_type(8)));
typedef float f32x4 __attribute__((ext_vector_type(4)));

static __device__ __forceinline__ f32x4 mfma16(bf16x8 a, bf16x8 b, f32x4 c) {
  return __builtin_amdgcn_mfma_f32_16x16x32_bf16(a, b, c, 0, 0, 0);
}

// -------- phase 0 (fused): w1t transpose + hjp + cnt --------
__global__ void k_pre(const float* __restrict__ h,
                      const float* __restrict__ msg_w1,
                      const float* __restrict__ msg_b1,
                      const int* __restrict__ emask,
                      __bf16* __restrict__ w1t, float* __restrict__ hjp,
                      float* __restrict__ cnt) {
  __shared__ float hr[128];
  __shared__ int csum;
  int j = blockIdx.x, t = threadIdx.x;
  if (t == 0) csum = 0;
  hr[t] = h[j * 128 + t];
  __syncthreads();
  float acc = msg_b1[t];
  #pragma unroll 8
  for (int k = 0; k < 128; k++) acc += hr[k] * msg_w1[k * 128 + t];
  hjp[j * 128 + t] = acc;
  // w1t[e][k] = msg_w1[128+k][e] : 32 elements per block
  if (t < 32) {
    int tt = j * 32 + t;
    int e = tt >> 7, k = tt & 127;
    w1t[e * 128 + k] = (__bf16)msg_w1[(128 + k) * 128 + e];
  }
  // cnt[j] = sum_r emask[r][j]
  int s = 0;
  #pragma unroll
  for (int r = 0; r < 4; r++) s += emask[(t * 4 + r) * NN + j] ? 1 : 0;
  #pragma unroll
  for (int off = 32; off > 0; off >>= 1) s += __shfl_down(s, off, 64);
  if ((t & 63) == 0) atomicAdd(&csum, s);
  __syncthreads();
  if (t == 0) cnt[j] = (float)csum;
}

// ---------------- phase 1: T[i][e] = sum_j mask[j,i]*silu(pre[j,i,e]) ----
// GEMM2 hoisted out of the N^2 loop. Two levers this round:
//  (a) mask-skip: mask[j,i]==0 rows contribute exactly 0 -> predicated
//      loads never fetch them (Bernoulli 0.5 -> rel traffic halves).
//  (b) 1-deep pipeline: current j's raw f32 kept in x0..x7; cvt at loop
//      top; next j's predicated loads issued before compute -> HBM latency
//      hidden under eg-compute. All register names static (rule #20).
// Live set ~111 VGPR; __launch_bounds__(256,2) keeps unified cap 256
// (cap 128 provokes the 64/64 arch/acc split + spills seen R1-R7).
#define LDS_BYTES 34816

#define LOADX(rp) \
  x0 = *(const f32x4*)(rp);       x1 = *(const f32x4*)((rp) + 4);  \
  x2 = *(const f32x4*)((rp) + 32); x3 = *(const f32x4*)((rp) + 36); \
  x4 = *(const f32x4*)((rp) + 64); x5 = *(const f32x4*)((rp) + 68); \
  x6 = *(const f32x4*)((rp) + 96); x7 = *(const f32x4*)((rp) + 100);

#define CVT(bf, xa, xb) { \
  bf[0] = (__bf16)xa[0]; bf[1] = (__bf16)xa[1]; \
  bf[2] = (__bf16)xa[2]; bf[3] = (__bf16)xa[3]; \
  bf[4] = (__bf16)xb[0]; bf[5] = (__bf16)xb[1]; \
  bf[6] = (__bf16)xb[2]; bf[7] = (__bf16)xb[3]; }

__global__ __launch_bounds__(256, 2) void k_main(
    const float* __restrict__ rel, const int* __restrict__ emask,
    const float* __restrict__ hjp, const __bf16* __restrict__ w1t_g,
    float* __restrict__ partial) {
  extern __shared__ char smem[];
  __bf16* w1t = (__bf16*)smem;
  const int tid = threadIdx.x;
  const int wave = tid >> 6;
  const int lane = tid & 63;
  const int l15 = lane & 15;
  const int q = lane >> 4;

  // stage w1t into padded LDS (row stride 272B): 256 thr x 8 bf16 x 8
  {
    int t = tid * 8;
    #pragma unroll
    for (int t0 = 0; t0 < 8; t0++) {
      int tt = t + t0 * 2048;
      int e = tt >> 7, k8 = tt & 127;
      *(bf16x8*)(w1t + e * 136 + k8) = *(const bf16x8*)(w1t_g + e * 128 + k8);
    }
  }
  __syncthreads();

  const int it = blockIdx.x >> 5;    // 0..31 : 16-row i-tile
  const int jc = blockIdx.x & 31;    // 0..31 : 16-col j-chunk
  const int irow = it * 16;

  // Tacc[ef][r] = T[i = l15][e = ef*16 + q*4 + r]
  f32x4 Tacc[8];
  #pragma unroll
  for (int ef = 0; ef < 8; ef++) {
    f32x4 z = {0.f, 0.f, 0.f, 0.f};
    Tacc[ef] = z;
  }

  const int jbase = jc * 16 + wave * 4;

  // prologue: zero raw regs once (uninitialized VGPRs could hold NaN bits;
  // after this, stale contents are finite rel data, safe under x*0)
  f32x4 x0 = {0.f, 0.f, 0.f, 0.f}, x1 = x0, x2 = x0, x3 = x0,
        x4 = x0, x5 = x0, x6 = x0, x7 = x0;
  float msCur = emask[(size_t)jbase * NN + irow + l15] ? 1.f : 0.f;
  {
    const float* rowp = rel + ((size_t)jbase * NN + irow + l15) * DD + q * 8;
    if (msCur != 0.f) { LOADX(rowp) }
  }

  #pragma unroll 1
  for (int jj = 0; jj < 4; jj++) {
    const int j = jbase + jj;

    // convert current j's raw f32 (loaded one iteration ago) to bf16 frags
    bf16x8 bfr0, bfr1, bfr2, bfr3;
    CVT(bfr0, x0, x1) CVT(bfr1, x2, x3) CVT(bfr2, x4, x5) CVT(bfr3, x6, x7)
    const float ms = msCur;
    const float* hj = hjp + (size_t)j * DD;

    // issue next j's predicated loads now (hidden under eg-compute below)
    float msn = 0.f;
    if (jj < 3) {
      msn = emask[(size_t)(j + 1) * NN + irow + l15] ? 1.f : 0.f;
      const float* rowp = rel + ((size_t)(j + 1) * NN + irow + l15) * DD + q * 8;
      if (msn != 0.f) { LOADX(rowp) }
    }
    msCur = msn;

    // per eg: GEMM1 rows [32eg,32eg+32) -> silu -> masked accumulate
    #pragma unroll
    for (int eg = 0; eg < 4; eg++) {
      f32x4 p0 = {0.f, 0.f, 0.f, 0.f};
      f32x4 p1 = {0.f, 0.f, 0.f, 0.f};
      #define G1(KC, BFR) \
        p0 = mfma16(*(const bf16x8*)(w1t + (eg * 32 + l15) * 136 + KC * 32 + q * 8), BFR, p0); \
        p1 = mfma16(*(const bf16x8*)(w1t + (eg * 32 + 16 + l15) * 136 + KC * 32 + q * 8), BFR, p1);
      G1(0, bfr0) G1(1, bfr1) G1(2, bfr2) G1(3, bfr3)
      #undef G1
      // lane holds pre[e = 32eg + q*4 + r][i = l15] (p0), e+16 (p1)
      f32x4 hv0 = *(const f32x4*)(hj + eg * 32 + q * 4);
      f32x4 hv1 = *(const f32x4*)(hj + eg * 32 + 16 + q * 4);
      #pragma unroll
      for (int r = 0; r < 4; r++) {
        float v0 = p0[r] + hv0[r];
        float v1 = p1[r] + hv1[r];
        Tacc[2 * eg][r]     += ms * v0 * __builtin_amdgcn_rcpf(1.f + __expf(-v0));
        Tacc[2 * eg + 1][r] += ms * v1 * __builtin_amdgcn_rcpf(1.f + __expf(-v1));
      }
    }
  }

  // cross-wave reduction: reuse w1t region as 4 x [8][132] f32 bufs.
  float* fbase = (float*)smem;
  float* fb = fbase + wave * (8 * 132);
  #pragma unroll
  for (int t = 0; t < 2; t++) {
    __syncthreads();
    if ((l15 >> 3) == t) {
      #pragma unroll
      for (int ef = 0; ef < 8; ef++)
        *(f32x4*)(fb + (l15 & 7) * 132 + ef * 16 + q * 4) = Tacc[ef];
    }
    __syncthreads();
    int row8 = tid >> 5;         // 0..7
    int e4 = (tid & 31) << 2;    // 0..124 step 4
    f32x4 s = {0.f, 0.f, 0.f, 0.f};
    #pragma unroll
    for (int w = 0; w < 4; w++)
      s += *(const f32x4*)(fbase + w * (8 * 132) + row8 * 132 + e4);
    *(f32x4*)(partial + ((size_t)jc * NN + irow + t * 8 + row8) * DD + e4) = s;
  }
}

// ------- phase 2: T-reduce + GEMM2(f32) + update MLP + LayerNorm -------
__global__ void k_update(const float* __restrict__ h, const float* __restrict__ partial,
                         const float* __restrict__ w2, const float* __restrict__ b2,
                         const float* __restrict__ cnt,
                         const float* __restrict__ uw1, const float* __restrict__ ub1,
                         const float* __restrict__ uw2, const float* __restrict__ ub2,
                         const float* __restrict__ g, const float* __restrict__ bb,
                         float* __restrict__ out) {
  __shared__ float Trow[128];
  __shared__ float uin[256];
  __shared__ float zl[128];
  __shared__ float ss[4];
  int i = blockIdx.x, t = threadIdx.x;
  float hv = h[i * 128 + t];
  float ts = 0.f;
  #pragma unroll
  for (int c = 0; c < 32; c++) ts += partial[((size_t)c * NN + i) * DD + t];
  Trow[t] = ts;
  __syncthreads();
  float a = cnt[i] * b2[t];
  #pragma unroll 8
  for (int e = 0; e < 128; e++) a += Trow[e] * w2[e * 128 + t];
  uin[t] = hv;
  uin[128 + t] = a;
  __syncthreads();
  float z = ub1[t];
  #pragma unroll 8
  for (int k = 0; k < 256; k++) z += uin[k] * uw1[k * 128 + t];
  z = z / (1.f + __expf(-z));
  zl[t] = z;
  __syncthreads();
  float dl = ub2[t];
  #pragma unroll 8
  for (int k = 0; k < 128; k++) dl += zl[k] * uw2[k * 128 + t];
  float x = hv + dl;
  float s1 = x, s2 = x * x;
  #pragma unroll
  for (int off = 32; off > 0; off >>= 1) {
    s1 += __shfl_down(s1, off, 64);
    s2 += __shfl_down(s2, off, 64);
  }
  if ((t & 63) == 0) { ss[(t >> 6) * 2] = s1; ss[(t >> 6) * 2 + 1] = s2; }
  __syncthreads();
  s1 = ss[0] + ss[2];
  s2 = ss[1] + ss[3];
  float mu = s1 * (1.f / 128.f);
  float var = s2 * (1.f / 128.f) - mu * mu;
  out[i * 128 + t] = (x - mu) * rsqrtf(var + 1e-5f) * g[t] + bb[t];
}

extern "C" void kernel_launch(void* const* d_in, const int* in_sizes, int n_in,
                              void* d_out, int out_size, void* d_ws, size_t ws_size,
                              hipStream_t stream) {
  const float* h      = (const float*)d_in[0];
  const float* rel    = (const float*)d_in[1];
  const int*   emask  = (const int*)d_in[2];
  const float* msg_w1 = (const float*)d_in[3];
  const float* msg_b1 = (const float*)d_in[4];
  const float* msg_w2 = (const float*)d_in[5];
  const float* msg_b2 = (const float*)d_in[6];
  const float* upd_w1 = (const float*)d_in[7];
  const float* upd_b1 = (const float*)d_in[8];
  const float* upd_w2 = (const float*)d_in[9];
  const float* upd_b2 = (const float*)d_in[10];
  const float* ln_g   = (const float*)d_in[11];
  const float* ln_b   = (const float*)d_in[12];
  float* out = (float*)d_out;

  char* ws = (char*)d_ws;
  float*  hjp     = (float*)ws;                        // 262144 B
  __bf16* w1t     = (__bf16*)(ws + 262144);            // 32768 B
  float*  cnt     = (float*)(ws + 262144 + 32768);     // 2048 B
  float*  partial = (float*)(ws + 262144 + 36864);     // 32*512*128*4 = 8 MiB

  k_pre<<<512, 128, 0, stream>>>(h, msg_w1, msg_b1, emask, w1t, hjp, cnt);
  hipFuncSetAttribute((const void*)k_main,
                      hipFuncAttributeMaxDynamicSharedMemorySize, LDS_BYTES);
  k_main<<<1024, 256, LDS_BYTES, stream>>>(rel, emask, hjp, w1t, partial);
  k_update<<<512, 128, 0, stream>>>(h, partial, msg_w2, msg_b2, cnt,
                                    upd_w1, upd_b1, upd_w2, upd_b2,
                                    ln_g, ln_b, out);
}